// Round 4
// baseline (409.332 us; speedup 1.0000x reference)
//
#include <hip/hip_runtime.h>

#define NELEM (4096 * 4096)
#define KDIM 4096
#define NDIM 4096
#define EPSQ 1e-8f
#define NBLK 512

typedef __attribute__((ext_vector_type(4))) int i32x4;
typedef __attribute__((address_space(3))) void lds_void;
typedef const __attribute__((address_space(1))) void gbl_void;

__device__ __forceinline__ void load_lds16(const void* g, void* l) {
    __builtin_amdgcn_global_load_lds((gbl_void*)g, (lds_void*)l, 16, 0, 0);
}

__device__ __forceinline__ float wave_max64(float v) {
#pragma unroll
    for (int off = 32; off > 0; off >>= 1)
        v = fmaxf(v, __shfl_down(v, off));
    return v;
}

// block-wide max of v; redf is a 4-float LDS scratch (reusable across calls)
__device__ __forceinline__ float block_max(float v, float* redf) {
    v = wave_max64(v);
    __syncthreads();                       // protect previous use of redf
    if ((threadIdx.x & 63) == 0) redf[threadIdx.x >> 6] = v;
    __syncthreads();
    return fmaxf(fmaxf(redf[0], redf[1]), fmaxf(redf[2], redf[3]));
}

// grid-wide barrier, poison-safe: gen is 1,2,3,... (never 0xAAAAAAAA).
// Requires all NBLK blocks co-resident (launch_bounds(256,2) on 512 blocks = 2/CU x 256 CU).
__device__ __forceinline__ void grid_barrier(unsigned* flags, unsigned* go, unsigned gen) {
    __syncthreads();
    if (blockIdx.x == 0) {
        if (threadIdx.x == 0)
            __hip_atomic_store(&flags[0], gen, __ATOMIC_RELEASE, __HIP_MEMORY_SCOPE_AGENT);
        // 256 threads watch 2 flags each (parallel gather of 512 arrivals)
        while (__hip_atomic_load(&flags[threadIdx.x], __ATOMIC_ACQUIRE, __HIP_MEMORY_SCOPE_AGENT) != gen)
            __builtin_amdgcn_s_sleep(1);
        while (__hip_atomic_load(&flags[threadIdx.x + 256], __ATOMIC_ACQUIRE, __HIP_MEMORY_SCOPE_AGENT) != gen)
            __builtin_amdgcn_s_sleep(1);
        __syncthreads();
        if (threadIdx.x == 0)
            __hip_atomic_store(go, gen, __ATOMIC_RELEASE, __HIP_MEMORY_SCOPE_AGENT);
    } else {
        if (threadIdx.x == 0) {
            __hip_atomic_store(&flags[blockIdx.x], gen, __ATOMIC_RELEASE, __HIP_MEMORY_SCOPE_AGENT);
            while (__hip_atomic_load(go, __ATOMIC_ACQUIRE, __HIP_MEMORY_SCOPE_AGENT) != gen)
                __builtin_amdgcn_s_sleep(1);
        }
    }
    __syncthreads();
}

// quantize 4 floats to int8 levels, pack into one int32
__device__ __forceinline__ int pack4(float4 a, float s, float qmax) {
    int b0 = (int)fminf(fmaxf(rintf(a.x / s), -qmax), qmax);  // rintf = round-half-even = jnp.round
    int b1 = (int)fminf(fmaxf(rintf(a.y / s), -qmax), qmax);
    int b2 = (int)fminf(fmaxf(rintf(a.z / s), -qmax), qmax);
    int b3 = (int)fminf(fmaxf(rintf(a.w / s), -qmax), qmax);
    return (b0 & 0xff) | ((b1 & 0xff) << 8) | ((b2 & 0xff) << 16) | (b3 << 24);
}

// ---- single fused kernel: absmax -> quant -> i8 GEMM -> out-quant ----
__global__ __launch_bounds__(256, 2) void fused_all(
    const float* __restrict__ x,   // [4096,4096]
    const float* __restrict__ w,   // [4096,4096] (out,in)
    const float* __restrict__ b,   // [4096]
    float* __restrict__ out,       // [4096,4096]
    char* __restrict__ ws)
{
    unsigned* flags  = (unsigned*)ws;            // [512]
    unsigned* go     = (unsigned*)(ws + 2048);   // [1]
    float* pmax_x = (float*)(ws + 4096);         // [512]
    float* pmax_w = (float*)(ws + 6144);         // [512]
    float* pmax_b = (float*)(ws + 8192);         // [1]
    float* omax   = (float*)(ws + 8448);         // [512]
    float* bq     = (float*)(ws + 12288);        // [4096]
    char*  qx     = ws + 32768;                  // 16 MB i8 [4096][4096]
    char*  qw     = qx + (size_t)NELEM;          // 16 MB i8 [4096][4096]

    const int bid = blockIdx.x, tid = threadIdx.x;
    __shared__ float redf[4];
    __shared__ char smA[128 * 64];               // 8 KB [128][64] row-major, NO pad (global_load_lds)
    __shared__ char smB[128 * 64];               // 8 KB

    // ================= phase A: per-block absmax partials =================
    {
        const float4* x4 = (const float4*)x;
        const float4* w4 = (const float4*)w;
        float mx = 0.f, mw = 0.f;
        for (int i = bid * 256 + tid; i < NELEM / 4; i += NBLK * 256) {
            float4 a = x4[i];
            mx = fmaxf(mx, fmaxf(fmaxf(fabsf(a.x), fabsf(a.y)), fmaxf(fabsf(a.z), fabsf(a.w))));
            float4 c = w4[i];
            mw = fmaxf(mw, fmaxf(fmaxf(fabsf(c.x), fabsf(c.y)), fmaxf(fabsf(c.z), fabsf(c.w))));
        }
        float mb = 0.f;
        if (bid == 0)
            for (int i = tid; i < NDIM; i += 256) mb = fmaxf(mb, fabsf(b[i]));
        mx = block_max(mx, redf);
        mw = block_max(mw, redf);
        mb = block_max(mb, redf);
        if (tid == 0) {
            pmax_x[bid] = mx;
            pmax_w[bid] = mw;
            if (bid == 0) pmax_b[0] = mb;
        }
    }
    grid_barrier(flags, go, 1u);

    // ================= reduce partials -> scales (every block) =================
    float vx = fmaxf(pmax_x[tid], pmax_x[tid + 256]);
    float vw = fmaxf(pmax_w[tid], pmax_w[tid + 256]);
    vx = block_max(vx, redf);
    vw = block_max(vw, redf);
    const float sx = fmaxf(vx / 127.0f, EPSQ);
    const float sw = fmaxf(vw / 7.0f, EPSQ);
    const float s = sx * sw;

    // ================= phase B: quantize x, w -> i8; b -> bq =================
    {
        const float4* x4 = (const float4*)x;
        const float4* w4 = (const float4*)w;
        int4* qx4 = (int4*)qx;
        int4* qw4 = (int4*)qw;
        for (int i = bid * 256 + tid; i < NELEM / 16; i += NBLK * 256) {
            int4 r;
            r.x = pack4(x4[i * 4 + 0], sx, 127.f);
            r.y = pack4(x4[i * 4 + 1], sx, 127.f);
            r.z = pack4(x4[i * 4 + 2], sx, 127.f);
            r.w = pack4(x4[i * 4 + 3], sx, 127.f);
            qx4[i] = r;
            int4 p;
            p.x = pack4(w4[i * 4 + 0], sw, 7.f);
            p.y = pack4(w4[i * 4 + 1], sw, 7.f);
            p.z = pack4(w4[i * 4 + 2], sw, 7.f);
            p.w = pack4(w4[i * 4 + 3], sw, 7.f);
            qw4[i] = p;
        }
        if (bid == 0) {
            const float sb = fmaxf(pmax_b[0] / 127.0f, EPSQ);
            for (int i = tid; i < NDIM; i += 256) {
                float q = fminf(fmaxf(rintf(b[i] / sb), -127.f), 127.f);
                bq[i] = q * sb;
            }
        }
    }
    grid_barrier(flags, go, 2u);

    // ================= phase C: i8 GEMM, 2 tiles of 128x128, acc in regs =================
    const int wave = tid >> 6, lane = tid & 63;
    const int wm = (wave & 1) * 64;      // wave's 64x64 quadrant
    const int wn = (wave >> 1) * 64;
    const int srow = wave * 16 + (lane >> 2);
    const int scol = (lane & 3) * 16;
    char* aL0 = smA + wave * 1024;       // wave-uniform LDS dst, lane*16B appended by HW
    char* aL1 = aL0 + 4096;
    char* bL0 = smB + wave * 1024;
    char* bL1 = bL0 + 4096;
    const int frow = lane & 15;          // fragment row within 16x16
    const int fk = (lane >> 4) * 16;     // byte k-offset of lane's 16 i8 elements

    i32x4 acc[2][4][4] = {};
    int bmv[2], bnv[2];

#pragma unroll
    for (int t = 0; t < 2; ++t) {
        const int tile = bid * 2 + t;    // adjacent bn share bm -> A-slab L2 reuse
        const int bm = tile >> 5, bn = tile & 31;
        bmv[t] = bm; bnv[t] = bn;
        const char* aP0 = qx + (long)(bm * 128 + srow) * KDIM + scol;
        const char* aP1 = aP0 + 64 * KDIM;
        const char* bP0 = qw + (long)(bn * 128 + srow) * KDIM + scol;
        const char* bP1 = bP0 + 64 * KDIM;

        for (int k0 = 0; k0 < KDIM; k0 += 64) {
            __syncthreads();             // previous tile's ds_reads done before overwrite
            load_lds16(aP0 + k0, aL0);
            load_lds16(aP1 + k0, aL1);
            load_lds16(bP0 + k0, bL0);
            load_lds16(bP1 + k0, bL1);
            __syncthreads();             // drains vmcnt(0) before barrier

            i32x4 af[4], bf[4];
#pragma unroll
            for (int i = 0; i < 4; ++i)
                af[i] = *(const i32x4*)(smA + (wm + i * 16 + frow) * 64 + fk);
#pragma unroll
            for (int j = 0; j < 4; ++j)
                bf[j] = *(const i32x4*)(smB + (wn + j * 16 + frow) * 64 + fk);
#pragma unroll
            for (int i = 0; i < 4; ++i)
#pragma unroll
                for (int j = 0; j < 4; ++j)
                    acc[t][i][j] = __builtin_amdgcn_mfma_i32_16x16x64_i8(af[i], bf[j], acc[t][i][j], 0, 0, 0);
        }
    }

    // out absmax over both register tiles (C/D layout: col=lane&15, row=(lane>>4)*4+reg)
    const int col = lane & 15;
    const int rbase = (lane >> 4) * 4;
    float bqv[2][4];
#pragma unroll
    for (int t = 0; t < 2; ++t)
#pragma unroll
        for (int j = 0; j < 4; ++j)
            bqv[t][j] = bq[bnv[t] * 128 + wn + j * 16 + col];

    float am = 0.f;
#pragma unroll
    for (int t = 0; t < 2; ++t)
#pragma unroll
        for (int i = 0; i < 4; ++i)
#pragma unroll
            for (int r = 0; r < 4; ++r)
#pragma unroll
                for (int j = 0; j < 4; ++j) {
                    float o = fmaf(s, (float)acc[t][i][j][r], bqv[t][j]);  // exact: |acc| <= 3.6M < 2^24
                    am = fmaxf(am, fabsf(o));
                }
    am = block_max(am, redf);
    if (tid == 0) omax[bid] = am;
    grid_barrier(flags, go, 3u);

    // ================= phase D: reduce out-scale, write final from regs =================
    float vo = fmaxf(omax[tid], omax[tid + 256]);
    vo = block_max(vo, redf);
    const float so = fmaxf(vo / 127.0f, EPSQ);

#pragma unroll
    for (int t = 0; t < 2; ++t)
#pragma unroll
        for (int i = 0; i < 4; ++i)
#pragma unroll
            for (int r = 0; r < 4; ++r) {
                const int m = bmv[t] * 128 + wm + i * 16 + rbase + r;
                float* orow = out + (long)m * NDIM + bnv[t] * 128 + wn + col;
#pragma unroll
                for (int j = 0; j < 4; ++j) {
                    float o = fmaf(s, (float)acc[t][i][j][r], bqv[t][j]);
                    float q = fminf(fmaxf(rintf(o / so), -127.f), 127.f) * so;
                    orow[j * 16] = q;
                }
            }
}

extern "C" void kernel_launch(void* const* d_in, const int* in_sizes, int n_in,
                              void* d_out, int out_size, void* d_ws, size_t ws_size,
                              hipStream_t stream) {
    const float* x = (const float*)d_in[0];
    const float* w = (const float*)d_in[1];
    const float* b = (const float*)d_in[2];
    float* out = (float*)d_out;
    char* ws = (char*)d_ws;

    hipLaunchKernelGGL(fused_all, dim3(NBLK), dim3(256), 0, stream, x, w, b, out, ws);
}